// Round 9
// baseline (105.649 us; speedup 1.0000x reference)
//
#include <hip/hip_runtime.h>

#define NB 8
#define DM 256
#define FD 96

using half8 = _Float16 __attribute__((ext_vector_type(8)));
using f32x4 = float __attribute__((ext_vector_type(4)));

__device__ __forceinline__ float clamp01(float x) { return fminf(fmaxf(x, 0.0f), 1.0f); }

// ---------------------------------------------------------------------------
// Kernel 0: precompute B = lin_w^T as f16 MFMA fragments into d_ws (48 KB).
// ---------------------------------------------------------------------------
__global__ void bprep_kernel(const float* __restrict__ lin_w,
                             _Float16* __restrict__ Bpre)
{
    const int fb = blockIdx.x * 256 + threadIdx.x;     // 0..3071
    const int ks = fb >> 10, nbv = (fb >> 6) & 15, ll = fb & 63;
    const float* lwrow = lin_w + (size_t)(nbv * 16 + (ll & 15)) * FD
                               + (ks * 32 + 4 * (ll >> 4));
    float4 lo = *reinterpret_cast<const float4*>(lwrow);
    float4 hi = *reinterpret_cast<const float4*>(lwrow + 16);
    half8 v;
    v[0] = (_Float16)lo.x; v[1] = (_Float16)lo.y; v[2] = (_Float16)lo.z; v[3] = (_Float16)lo.w;
    v[4] = (_Float16)hi.x; v[5] = (_Float16)hi.y; v[6] = (_Float16)hi.z; v[7] = (_Float16)hi.w;
    *reinterpret_cast<half8*>(Bpre + (size_t)fb * 8) = v;
}

// ---------------------------------------------------------------------------
// Kernel A: sim with 2 lanes per position. Lane sub = gtid&1 owns global
// blocks sub*4..sub*4+3 (W rows + h quarters); partner half of h mirrored
// each step via __shfl_xor(...,1) (DPP, no LDS). Local column order: own half
// first -> ALL register arrays statically indexed; only LDS/global addresses
// depend on sub. Grid 2x: 4096 waves = 4 waves/SIMD (was grid-limited 2).
// Flush transposes are wave-private (no barriers needed).
// ---------------------------------------------------------------------------
__global__ __launch_bounds__(256, 1) void bio_sim_kernel(
    const int* __restrict__ bits,
    const float* __restrict__ stim_in,
    const float* __restrict__ Winit,
    const int* __restrict__ steps_ptr,
    float* __restrict__ out_h,
    float* __restrict__ out_W,
    int npos)
{
    const int tid  = threadIdx.x;
    const int gtid = blockIdx.x * 256 + tid;
    const int pos  = gtid >> 1;
    const int sub  = gtid & 1;
    const int steps = steps_ptr[0];

    float h[8][4];   // local order: 0..3 own half, 4..7 partner half
    float W[4][8];   // own 4 rows x 8 local cols

    // ---- decode own 4 blocks
    const int4* bp = reinterpret_cast<const int4*>(bits + (size_t)pos * 64 + sub * 32);
    #pragma unroll
    for (int b = 0; b < 4; ++b) {
        int4 lo = bp[2 * b + 0];
        int4 hi = bp[2 * b + 1];
        h[b][0] = (float)(lo.x * 2 + lo.y) / 3.0f;
        h[b][1] = (float)(lo.z * 2 + lo.w) / 3.0f;
        h[b][2] = (float)(hi.x * 2 + hi.y) / 3.0f;
        h[b][3] = (float)(hi.z * 2 + hi.w) / 3.0f;
    }
    #pragma unroll
    for (int b = 0; b < 4; ++b)
        #pragma unroll
        for (int c = 0; c < 4; ++c)
            h[4 + b][c] = __shfl_xor(h[b][c], 1, 64);

    // ---- own W rows, local col order (own half cols first), zero diag
    const int co_own = sub * 4;          // global col offset of own half
    const int co_oth = 4 - sub * 4;      // global col offset of partner half
    #pragma unroll
    for (int i = 0; i < 4; ++i) {
        const float* rowp = Winit + (size_t)pos * 64 + (size_t)(co_own + i) * 8;
        float4 a = *reinterpret_cast<const float4*>(rowp + co_own);
        float4 b = *reinterpret_cast<const float4*>(rowp + co_oth);
        W[i][0] = a.x; W[i][1] = a.y; W[i][2] = a.z; W[i][3] = a.w;
        W[i][4] = b.x; W[i][5] = b.y; W[i][6] = b.z; W[i][7] = b.w;
        W[i][i] = 0.0f;                  // local diag == global diag
    }

    const float stim = stim_in[pos];

    for (int st = 0; st < steps; ++st) {
        float nb[4][4];
        #pragma unroll
        for (int i = 0; i < 4; ++i) {
            float s0 = 0.f, s1 = 0.f, s2 = 0.f, s3 = 0.f, tw = 0.f;
            #pragma unroll
            for (int j = 0; j < 8; ++j) {
                float w = W[i][j];
                s0 += w * h[j][0];
                s1 += w * h[j][1];
                s2 += w * h[j][2];
                s3 += w * h[j][3];
                tw += w;
            }
            float inv = __builtin_amdgcn_rcpf(tw + 1e-8f);
            nb[i][0] = s0 * inv; nb[i][1] = s1 * inv;
            nb[i][2] = s2 * inv; nb[i][3] = s3 * inv;
        }
        #pragma unroll
        for (int i = 0; i < 4; ++i) {
            float E = h[i][0], P = h[i][1], G = h[i][2], L = h[i][3];
            float En = nb[i][0], Pn = nb[i][1], Gn = nb[i][2], Ln = nb[i][3];
            float E_new = clamp01(E + 0.3f * stim - 0.4f * P - 0.2f * G);
            float P_new = clamp01(P + 0.5f * stim + 0.3f * (Pn - P) - 0.2f * E);
            float G_new = clamp01(G + 0.4f * E * (1.0f - P) + 0.2f * (Gn - G) - 0.3f * P);
            float good  = 0.5f * En + 0.5f * Gn;
            float L_new = clamp01(L + 0.4f * good + 0.3f * (Ln - L) - 0.3f * P);
            h[i][0] = E_new; h[i][1] = P_new; h[i][2] = G_new; h[i][3] = L_new;
        }
        // mirror partner's updated half
        #pragma unroll
        for (int b = 0; b < 4; ++b)
            #pragma unroll
            for (int c = 0; c < 4; ++c)
                h[4 + b][c] = __shfl_xor(h[b][c], 1, 64);
        // W update: own rows only. i<j over local indices; intra-half pairs
        // update both sides (both owned); cross-half only own side.
        #pragma unroll
        for (int i = 0; i < 4; ++i) {
            #pragma unroll
            for (int j = i + 1; j < 8; ++j) {
                float d0 = h[i][0] - h[j][0];
                float d1 = h[i][1] - h[j][1];
                float d2 = h[i][2] - h[j][2];
                float d3 = h[i][3] - h[j][3];
                float q = d0 * d0 + d1 * d1 + d2 * d2 + d3 * d3;
                float dist = __builtin_amdgcn_sqrtf(q);    // sqrt(0)=0: guard-free
                float inc = 0.1f * (0.5f * (h[i][3] + h[j][3])) * dist;
                W[i][j] = clamp01(W[i][j] + inc - 0.05f * W[i][j]);
                if (j < 4)
                    W[j][i] = clamp01(W[j][i] + inc - 0.05f * W[j][i]);
            }
        }
    }

    // ---- wave-private LDS transpose (8 KB/wave, no barriers: exclusive region)
    __shared__ float xpose[4][2048];
    const int w = tid >> 6;
    const int l = tid & 63;
    float* buf = xpose[w];
    const int posBase = blockIdx.x * 128 + w * 32;   // 32 positions per wave

    // W: flat = (l>>1)*64 + globalfeat = l*32 + (i*8+gc);  gc = global col
    #pragma unroll
    for (int i = 0; i < 4; ++i) {
        #pragma unroll
        for (int lb = 0; lb < 8; ++lb) {
            const int gc = (lb < 4) ? (co_own + lb) : (co_oth + lb - 4);
            const int kg = i * 8 + gc;
            buf[l * 32 + (kg ^ (l & 31))] = W[i][lb];
        }
    }
    {
        float* dst = out_W + (size_t)posBase * 64;
        #pragma unroll
        for (int i2 = 0; i2 < 32; ++i2) {
            const int r = i2 * 2 + (l >> 5);
            dst[i2 * 64 + l] = buf[r * 32 + ((l & 31) ^ (r & 31))];  // 256B/inst
        }
    }
    // h: flat = l*16 + k, k = i*4+ch (global feat = sub*16+k via address)
    #pragma unroll
    for (int i = 0; i < 4; ++i) {
        #pragma unroll
        for (int c = 0; c < 4; ++c) {
            const int k = i * 4 + c;
            buf[l * 16 + (k ^ ((l >> 1) & 15))] = h[i][c];
        }
    }
    {
        float* dst = out_h + (size_t)posBase * 32;
        #pragma unroll
        for (int i2 = 0; i2 < 16; ++i2) {
            const int r = i2 * 4 + (l >> 4);
            const int s = (r >> 1) & 15;
            dst[i2 * 64 + l] = buf[r * 16 + ((l & 15) ^ s)];         // 256B/inst
        }
    }
}

// ---------------------------------------------------------------------------
// Kernel B: emb = phys @ lin_w^T + lin_b via f16 MFMA.  (unchanged, ~24 us,
// at its 134 MB write floor)
// ---------------------------------------------------------------------------
__global__ __launch_bounds__(256, 4) void einsum_mfma_kernel(
    const float* __restrict__ hsrc,
    const float* __restrict__ wsrc,
    const _Float16* __restrict__ Bpre,
    const float* __restrict__ lin_b,
    float* __restrict__ out_emb)
{
    __shared__ float Cbuf[64 * 132];
    const int tid = threadIdx.x;
    const int w = tid >> 6, l = tid & 63;
    const int pos0 = blockIdx.x * 64;

    const int arow = pos0 + w * 16 + (l & 15);
    const int koff = 4 * (l >> 4);
    half8 afr[3];
    {
        const float* s0 = hsrc + (size_t)arow * 32 + koff;
        float4 lo = *reinterpret_cast<const float4*>(s0);
        float4 hi = *reinterpret_cast<const float4*>(s0 + 16);
        afr[0][0] = (_Float16)lo.x; afr[0][1] = (_Float16)lo.y;
        afr[0][2] = (_Float16)lo.z; afr[0][3] = (_Float16)lo.w;
        afr[0][4] = (_Float16)hi.x; afr[0][5] = (_Float16)hi.y;
        afr[0][6] = (_Float16)hi.z; afr[0][7] = (_Float16)hi.w;
        #pragma unroll
        for (int ks = 1; ks < 3; ++ks) {
            const float* s = wsrc + (size_t)arow * 64 + (ks - 1) * 32 + koff;
            float4 a = *reinterpret_cast<const float4*>(s);
            float4 b = *reinterpret_cast<const float4*>(s + 16);
            afr[ks][0] = (_Float16)a.x; afr[ks][1] = (_Float16)a.y;
            afr[ks][2] = (_Float16)a.z; afr[ks][3] = (_Float16)a.w;
            afr[ks][4] = (_Float16)b.x; afr[ks][5] = (_Float16)b.y;
            afr[ks][6] = (_Float16)b.z; afr[ks][7] = (_Float16)b.w;
        }
    }

    f32x4 acc[16];
    #pragma unroll
    for (int nbv = 0; nbv < 16; ++nbv) acc[nbv] = (f32x4){0.f, 0.f, 0.f, 0.f};
    #pragma unroll
    for (int ks = 0; ks < 3; ++ks) {
        #pragma unroll
        for (int nbv = 0; nbv < 16; ++nbv) {
            half8 b = *reinterpret_cast<const half8*>(Bpre + (size_t)((ks * 16 + nbv) * 64 + l) * 8);
            acc[nbv] = __builtin_amdgcn_mfma_f32_16x16x32_f16(afr[ks], b, acc[nbv], 0, 0, 0);
        }
    }

    #pragma unroll
    for (int c = 0; c < 2; ++c) {
        #pragma unroll
        for (int nn = 0; nn < 8; ++nn) {
            const int nbv = c * 8 + nn;
            #pragma unroll
            for (int r = 0; r < 4; ++r) {
                const int row = w * 16 + 4 * (l >> 4) + r;
                Cbuf[row * 132 + nn * 16 + (l & 15)] = acc[nbv][r];
            }
        }
        __syncthreads();
        const float4 biasv = reinterpret_cast<const float4*>(lin_b)[c * 32 + (l & 31)];
        #pragma unroll
        for (int rep = 0; rep < 8; ++rep) {
            const int row = w * 16 + rep * 2 + (l >> 5);
            float4 v = *reinterpret_cast<const float4*>(Cbuf + row * 132 + (l & 31) * 4);
            v.x += biasv.x; v.y += biasv.y; v.z += biasv.z; v.w += biasv.w;
            *reinterpret_cast<float4*>(out_emb + (size_t)(pos0 + row) * DM + c * 128 + (l & 31) * 4) = v;
        }
        __syncthreads();
    }
}

extern "C" void kernel_launch(void* const* d_in, const int* in_sizes, int n_in,
                              void* d_out, int out_size, void* d_ws, size_t ws_size,
                              hipStream_t stream) {
    const int*   bits  = (const int*)d_in[0];
    const float* stim  = (const float*)d_in[1];
    const float* Winit = (const float*)d_in[2];
    const float* lin_w = (const float*)d_in[3];
    const float* lin_b = (const float*)d_in[4];
    const int*   steps = (const int*)d_in[5];

    const int npos = in_sizes[1];   // B*S = 131072

    float* out_emb = (float*)d_out;
    float* out_h   = out_emb + (size_t)npos * DM;
    float* out_W   = out_h + (size_t)npos * 32;
    _Float16* Bpre = (_Float16*)d_ws;            // 48 KB fragment buffer

    hipLaunchKernelGGL(bprep_kernel, dim3(12), dim3(256), 0, stream, lin_w, Bpre);
    hipLaunchKernelGGL(bio_sim_kernel, dim3(npos / 128), dim3(256), 0, stream,
                       bits, stim, Winit, steps, out_h, out_W, npos);
    hipLaunchKernelGGL(einsum_mfma_kernel, dim3(npos / 64), dim3(256), 0, stream,
                       out_h, out_W, Bpre, lin_b, out_emb);
}